// Round 4
// baseline (89.614 us; speedup 1.0000x reference)
//
#include <hip/hip_runtime.h>

// CostVolume: out (1, 2C, D4, H, W) fp32
//   c <  C : left [c,h,w]     if w >= d else 0
//   c >= C : right[c-C,h,w-d] if w >= d else 0
// C=32, H=128, W=240, D4=48.
//
// Write-BW-bound (377.5 MB out). R3 showed 960B-granular write scatter costs
// ~30% vs the dense-fill ceiling. This version: one block per (c2,d) slice,
// writing a CONTIGUOUS 122,880 B region with all 64 lanes active; reads
// gather from the (c2) channel image via L2 (48 consecutive blocks share it).

constexpr int C      = 32;
constexpr int H      = 128;
constexpr int W      = 240;
constexpr int D4     = 48;
constexpr int W4     = W / 4;          // 60 float4 per row
constexpr int SLICE4 = H * W4;         // 7680 float4 per (c2,d) slice
constexpr int BLOCK  = 256;
constexpr int ITERS  = SLICE4 / BLOCK; // 30, exact

typedef float f32x4 __attribute__((ext_vector_type(4)));

__global__ void __launch_bounds__(256) cost_volume_kernel(
    const float* __restrict__ left,
    const float* __restrict__ right,
    float* __restrict__ out) {
    const int slice = blockIdx.x;       // c2*D4 + d
    const int d     = slice % D4;       // uniform per block
    const int c2    = slice / D4;
    const bool is_left = (c2 < C);

    f32x4* __restrict__ out4 =
        reinterpret_cast<f32x4*>(out) + (long)slice * SLICE4;
    const int tid = threadIdx.x;

    if (is_left) {
        // left: value = left[c2,h,w] masked by w>=d. Source float4 index for
        // output flat index (h*60+w4) is... flat itself. Aligned vector load.
        const f32x4* __restrict__ src4 =
            reinterpret_cast<const f32x4*>(left + c2 * H * W);
#pragma unroll 6
        for (int it = 0; it < ITERS; ++it) {
            const int flat = it * BLOCK + tid;
            const int w0   = (flat % W4) * 4;
            f32x4 v = src4[flat];
            if (w0 < d) {               // mask only touches w4 < 12
#pragma unroll
                for (int j = 0; j < 4; ++j)
                    if (w0 + j < d) v[j] = 0.0f;
            }
            __builtin_nontemporal_store(v, out4 + flat);
        }
    } else {
        // right: value = right[c2-C,h,w-d] masked by w>=d. Shift d is block-
        // uniform; per-lane gather of 4 dwords (L1/L2-resident source).
        const float* __restrict__ src = right + (c2 - C) * H * W;
#pragma unroll 6
        for (int it = 0; it < ITERS; ++it) {
            const int flat = it * BLOCK + tid;
            const int h    = flat / W4;
            const int w0   = (flat % W4) * 4;
            const float* __restrict__ row = src + h * W - d;
            f32x4 v;
#pragma unroll
            for (int j = 0; j < 4; ++j) {
                const int wj = w0 + j;
                v[j] = (wj >= d) ? row[wj] : 0.0f;
            }
            __builtin_nontemporal_store(v, out4 + flat);
        }
    }
}

extern "C" void kernel_launch(void* const* d_in, const int* in_sizes, int n_in,
                              void* d_out, int out_size, void* d_ws,
                              size_t ws_size, hipStream_t stream) {
    const float* left  = (const float*)d_in[0];
    const float* right = (const float*)d_in[1];
    float* out = (float*)d_out;

    const int grid = 2 * C * D4;   // 3072 blocks, one per (c2,d) slice
    cost_volume_kernel<<<grid, BLOCK, 0, stream>>>(left, right, out);
}

// Round 5
// 78.697 us; speedup vs baseline: 1.1387x; 1.1387x over previous
//
#include <hip/hip_runtime.h>

// CostVolume: out (1, 2C, D4, H, W) fp32
//   c <  C : left [c,h,w]     if w >= d else 0
//   c >= C : right[c-C,h,w-d] if w >= d else 0
// C=32, H=128, W=240, D4=48.  Write-BW-bound: 377.5 MB out.
//
// R3 (row-stage, 960B write chunks, 60/64 lanes): 77.4 us = 4.88 TB/s.
// R4 (contiguous slices, per-iter global gathers): 89.6 us — gather chains
// cost more than contiguity gained. This round: LDS-staged reads (R3's win)
// + 7.7 KB contiguous full-lane write units per (block,d).
// Block = (c2, 8-row chunk): stage 8 rows (1920 dwords) in padded LDS once,
// then 48 d-slices; per d all 256 threads write 480 float4 contiguous.

constexpr int C   = 32;
constexpr int H   = 128;
constexpr int W   = 240;
constexpr int D4  = 48;
constexpr int W4  = W / 4;            // 60 float4 per row
constexpr int RPB = 8;                // rows per block
constexpr int HC  = H / RPB;          // 16 h-chunks
constexpr int CH4 = RPB * W4;         // 480 float4 per chunk
constexpr int BLOCK = 256;
constexpr int PAD_OFF = 48;           // guard so (w - d) reads stay >= 0

typedef float f32x4 __attribute__((ext_vector_type(4)));

// +1 dword pad per 32 so stride-4-dword lane access spreads across all banks
__device__ __forceinline__ int pidx(int x) { return x + (x >> 5); }

__global__ void __launch_bounds__(256) cost_volume_kernel(
    const float* __restrict__ left,
    const float* __restrict__ right,
    float* __restrict__ out) {
    __shared__ float rowbuf[2080];     // pidx(PAD_OFF+1919)=2028 max

    const int blk = blockIdx.x;        // c2*HC + hc
    const int hc  = blk % HC;
    const int c2  = blk / HC;
    const int h0  = hc * RPB;
    const int tid = threadIdx.x;
    const bool is_left = (c2 < C);

    f32x4* __restrict__ outb = reinterpret_cast<f32x4*>(out)
        + ((long)(c2 * D4) * H + h0) * W4;          // d=0 base of this chunk
    const long dstride = (long)H * W4;               // 7680 float4 between d

    const int f0  = tid;                             // flat float4 idx, pass 0
    const int f1  = tid + BLOCK;                     // pass 1 (valid if <480)
    const bool has1 = (f1 < CH4);
    const int f1c = has1 ? f1 : (CH4 - 1);           // clamp for safe indexing
    const int w0_0 = (f0 % W4) * 4;                  // element w of lane start
    const int w0_1 = (f1c % W4) * 4;

    if (is_left) {
        // Source float4 layout == output slice layout: cache chunk in regs,
        // re-store 48x with the per-d mask. Zero re-reads.
        const f32x4* __restrict__ src4 =
            reinterpret_cast<const f32x4*>(left + (c2 * H + h0) * W);
        const f32x4 t0 = src4[f0];
        const f32x4 t1 = has1 ? src4[f1] : f32x4{0.f, 0.f, 0.f, 0.f};
#pragma unroll 4
        for (int d = 0; d < D4; ++d) {
            f32x4 v0, v1;
#pragma unroll
            for (int j = 0; j < 4; ++j) {
                v0[j] = (w0_0 + j >= d) ? t0[j] : 0.0f;
                v1[j] = (w0_1 + j >= d) ? t1[j] : 0.0f;
            }
            f32x4* __restrict__ o = outb + d * dstride;
            __builtin_nontemporal_store(v0, o + f0);
            if (has1) __builtin_nontemporal_store(v1, o + f1);
        }
    } else {
        // Stage 8 rows once; per d, shifted scalar LDS reads (conflict-free
        // via pad), contiguous full-lane stores.
        const float* __restrict__ src = right + ((c2 - C) * H + h0) * W;
        for (int f = tid; f < CH4; f += BLOCK) {
            f32x4 t = reinterpret_cast<const f32x4*>(src)[f];
            const int base = PAD_OFF + f * 4;
#pragma unroll
            for (int j = 0; j < 4; ++j) rowbuf[pidx(base + j)] = t[j];
        }
        __syncthreads();
        const int b0 = PAD_OFF + (f0  / W4) * W + w0_0;  // dword idx of (r,w0)
        const int b1 = PAD_OFF + (f1c / W4) * W + w0_1;
#pragma unroll 4
        for (int d = 0; d < D4; ++d) {
            f32x4 v0, v1;
#pragma unroll
            for (int j = 0; j < 4; ++j) {
                // b - d + j >= PAD_OFF - 47 >= 1: always in-bounds
                v0[j] = (w0_0 + j >= d) ? rowbuf[pidx(b0 - d + j)] : 0.0f;
                v1[j] = (w0_1 + j >= d) ? rowbuf[pidx(b1 - d + j)] : 0.0f;
            }
            f32x4* __restrict__ o = outb + d * dstride;
            __builtin_nontemporal_store(v0, o + f0);
            if (has1) __builtin_nontemporal_store(v1, o + f1);
        }
    }
}

extern "C" void kernel_launch(void* const* d_in, const int* in_sizes, int n_in,
                              void* d_out, int out_size, void* d_ws,
                              size_t ws_size, hipStream_t stream) {
    const float* left  = (const float*)d_in[0];
    const float* right = (const float*)d_in[1];
    float* out = (float*)d_out;

    const int grid = 2 * C * HC;   // 1024 blocks: one per (c2, 8-row chunk)
    cost_volume_kernel<<<grid, BLOCK, 0, stream>>>(left, right, out);
}

// Round 6
// 77.636 us; speedup vs baseline: 1.1543x; 1.0137x over previous
//
#include <hip/hip_runtime.h>

// CostVolume: out (1, 2C, D4, H, W) fp32
//   c <  C : left [c,h,w]     if w >= d else 0
//   c >= C : right[c-C,h,w-d] if w >= d else 0
// C=32, H=128, W=240, D4=48.  Write-BW-bound: 377.5 MB out.
//
// R3 (960B chunks) 77.4us == R5 (7.7KB chunks) 78.7us -> write granularity
// is NOT the limiter. Single-variable A/B this round: drop the nontemporal
// flag (used in every prior round). The 6.86 TB/s reference fill uses plain
// stores; NT may defeat L2 write-combining on gfx950.

constexpr int C   = 32;
constexpr int H   = 128;
constexpr int W   = 240;
constexpr int D4  = 48;
constexpr int W4  = W / 4;            // 60 float4 per row
constexpr int RPB = 8;                // rows per block
constexpr int HC  = H / RPB;          // 16 h-chunks
constexpr int CH4 = RPB * W4;         // 480 float4 per chunk
constexpr int BLOCK = 256;
constexpr int PAD_OFF = 48;           // guard so (w - d) reads stay >= 0

typedef float f32x4 __attribute__((ext_vector_type(4)));

// +1 dword pad per 32 so stride-4-dword lane access spreads across all banks
__device__ __forceinline__ int pidx(int x) { return x + (x >> 5); }

__global__ void __launch_bounds__(256) cost_volume_kernel(
    const float* __restrict__ left,
    const float* __restrict__ right,
    float* __restrict__ out) {
    __shared__ float rowbuf[2080];     // pidx(PAD_OFF+1919)=2028 max

    const int blk = blockIdx.x;        // c2*HC + hc
    const int hc  = blk % HC;
    const int c2  = blk / HC;
    const int h0  = hc * RPB;
    const int tid = threadIdx.x;
    const bool is_left = (c2 < C);

    f32x4* __restrict__ outb = reinterpret_cast<f32x4*>(out)
        + ((long)(c2 * D4) * H + h0) * W4;          // d=0 base of this chunk
    const long dstride = (long)H * W4;               // 7680 float4 between d

    const int f0  = tid;                             // flat float4 idx, pass 0
    const int f1  = tid + BLOCK;                     // pass 1 (valid if <480)
    const bool has1 = (f1 < CH4);
    const int f1c = has1 ? f1 : (CH4 - 1);           // clamp for safe indexing
    const int w0_0 = (f0 % W4) * 4;                  // element w of lane start
    const int w0_1 = (f1c % W4) * 4;

    if (is_left) {
        // Source float4 layout == output slice layout: cache chunk in regs,
        // re-store 48x with the per-d mask. Zero re-reads.
        const f32x4* __restrict__ src4 =
            reinterpret_cast<const f32x4*>(left + (c2 * H + h0) * W);
        const f32x4 t0 = src4[f0];
        const f32x4 t1 = has1 ? src4[f1] : f32x4{0.f, 0.f, 0.f, 0.f};
#pragma unroll 4
        for (int d = 0; d < D4; ++d) {
            f32x4 v0, v1;
#pragma unroll
            for (int j = 0; j < 4; ++j) {
                v0[j] = (w0_0 + j >= d) ? t0[j] : 0.0f;
                v1[j] = (w0_1 + j >= d) ? t1[j] : 0.0f;
            }
            f32x4* __restrict__ o = outb + d * dstride;
            o[f0] = v0;                       // plain store (A/B vs nt)
            if (has1) o[f1] = v1;
        }
    } else {
        // Stage 8 rows once; per d, shifted scalar LDS reads (conflict-free
        // via pad), contiguous full-lane stores.
        const float* __restrict__ src = right + ((c2 - C) * H + h0) * W;
        for (int f = tid; f < CH4; f += BLOCK) {
            f32x4 t = reinterpret_cast<const f32x4*>(src)[f];
            const int base = PAD_OFF + f * 4;
#pragma unroll
            for (int j = 0; j < 4; ++j) rowbuf[pidx(base + j)] = t[j];
        }
        __syncthreads();
        const int b0 = PAD_OFF + (f0  / W4) * W + w0_0;  // dword idx of (r,w0)
        const int b1 = PAD_OFF + (f1c / W4) * W + w0_1;
#pragma unroll 4
        for (int d = 0; d < D4; ++d) {
            f32x4 v0, v1;
#pragma unroll
            for (int j = 0; j < 4; ++j) {
                // b - d + j >= PAD_OFF - 47 >= 1: always in-bounds
                v0[j] = (w0_0 + j >= d) ? rowbuf[pidx(b0 - d + j)] : 0.0f;
                v1[j] = (w0_1 + j >= d) ? rowbuf[pidx(b1 - d + j)] : 0.0f;
            }
            f32x4* __restrict__ o = outb + d * dstride;
            o[f0] = v0;                       // plain store (A/B vs nt)
            if (has1) o[f1] = v1;
        }
    }
}

extern "C" void kernel_launch(void* const* d_in, const int* in_sizes, int n_in,
                              void* d_out, int out_size, void* d_ws,
                              size_t ws_size, hipStream_t stream) {
    const float* left  = (const float*)d_in[0];
    const float* right = (const float*)d_in[1];
    float* out = (float*)d_out;

    const int grid = 2 * C * HC;   // 1024 blocks: one per (c2, 8-row chunk)
    cost_volume_kernel<<<grid, BLOCK, 0, stream>>>(left, right, out);
}